// Round 10
// baseline (193.561 us; speedup 1.0000x reference)
//
#include <hip/hip_runtime.h>

typedef unsigned short u16;
typedef unsigned int u32;
typedef __attribute__((ext_vector_type(8))) short bf16x8;
typedef __attribute__((ext_vector_type(4))) float f32x4;
typedef __attribute__((ext_vector_type(16))) float f32x16;
typedef __attribute__((ext_vector_type(4))) u32 u32x4;

#define D_MODEL 1024
#define NHEAD 16
#define DHEAD 64
#define SEQ 2048
#define BATCH 4
#define MTOT (BATCH * SEQ) /* 8192 */
#define LOG2E 1.4426950408889634f

#define MFMA16(A, B, C) __builtin_amdgcn_mfma_f32_16x16x32_bf16((A), (B), (C), 0, 0, 0)
#define MFMA32(A, B, C) __builtin_amdgcn_mfma_f32_32x32x16_bf16((A), (B), (C), 0, 0, 0)

__device__ __forceinline__ u16 f2bf(float f) {
  u32 u = __builtin_bit_cast(u32, f);
  u = (u + 0x7FFFu + ((u >> 16) & 1u)) >> 16;
  return (u16)u;
}

// async global->LDS, 16B per lane. lds must be wave-uniform; g is per-lane.
__device__ __forceinline__ void async_copy16(void* lds, const void* g) {
  __builtin_amdgcn_global_load_lds(
      (const __attribute__((address_space(1))) u32*)g,
      (__attribute__((address_space(3))) u32*)lds, 16, 0, 0);
}

__device__ __forceinline__ u32 cvtpk_bf16(float lo, float hi) {
  u32 r;
  asm("v_cvt_pk_bf16_f32 %0, %1, %2" : "=v"(r) : "v"(lo), "v"(hi));
  return r;
}
// swaps a.hi32lanes <-> b.lo32lanes
__device__ __forceinline__ void permswap(u32& a, u32& b) {
  asm("v_permlane32_swap_b32 %0, %1" : "+v"(a), "+v"(b));
}

// raw workgroup barrier WITHOUT vmcnt drain (T4); memory-clobbered + sched-fenced
__device__ __forceinline__ void wg_barrier() {
  __builtin_amdgcn_sched_barrier(0);
  asm volatile("s_barrier" ::: "memory");
  __builtin_amdgcn_sched_barrier(0);
}
#define VMCNT(N) asm volatile("s_waitcnt vmcnt(" #N ")" ::: "memory")

// ---------------- fp32 -> bf16 convert (all six tensors, one launch) ----------------
__global__ void cvt_all(const float* __restrict__ x, const float* __restrict__ ctx,
                        const float* __restrict__ Wq, const float* __restrict__ Wk,
                        const float* __restrict__ Wv, const float* __restrict__ Wo,
                        u16* __restrict__ xb, u16* __restrict__ cb,
                        u16* __restrict__ wqb, u16* __restrict__ wkb,
                        u16* __restrict__ wvb, u16* __restrict__ wob) {
  const int NX = 1 << 21;                 // x / ctx in float4 units (8M/4)
  const int NW = 1 << 18;                 // each weight in float4 units (1M/4)
  const int total = 2 * NX + 4 * NW;
  int i = blockIdx.x * blockDim.x + threadIdx.x;
  const int st = gridDim.x * blockDim.x;
  for (; i < total; i += st) {
    const float* s; u16* d; int j;
    if (i < NX)            { s = x;   d = xb;  j = i; }
    else if (i < 2 * NX)   { s = ctx; d = cb;  j = i - NX; }
    else {
      int k = i - 2 * NX;
      int wi = k >> 18;
      j = k & (NW - 1);
      s = (wi == 0) ? Wq : (wi == 1) ? Wk : (wi == 2) ? Wv : Wo;
      d = (wi == 0) ? wqb : (wi == 1) ? wkb : (wi == 2) ? wvb : wob;
    }
    float4 v = ((const float4*)s)[j];
    ushort4 o;
    o.x = f2bf(v.x); o.y = f2bf(v.y); o.z = f2bf(v.z); o.w = f2bf(v.w);
    ((ushort4*)d)[j] = o;
  }
}

// ================= fused QKV NT-GEMM =================
// grid 1536: swz<512 -> Q = x·Wq^T (+bq, qknorm, *log2e) -> Qb
//            swz>=512 -> [K|V] = ctx·[Wk;Wv]^T; cols<1024: K (+bk, qknorm) -> Kb
//            cols>=1024: V (+bv) -> Vfb in PRE-FRAGMENTED layout:
//              frag(bh, t, sl, dt) is 1KB; lane l holds dh=dt*32+(l&31),
//              toks t*64+sl*16+(l>>5)*8..+8  == mfma_32x32x16 A-operand.
__global__ __launch_bounds__(256, 3) void gemm_qkv(
    const u16* __restrict__ xb, const u16* __restrict__ cb,
    const u16* __restrict__ wqb, const u16* __restrict__ wkvb,
    const float* __restrict__ bq, const float* __restrict__ bk,
    const float* __restrict__ bv,
    u16* __restrict__ Qb, u16* __restrict__ Kb, u16* __restrict__ Vfb) {
  __shared__ u16 As[128 * 64]; // 16KB, rows 128B, granule-swizzled g^=(row&7)
  __shared__ u16 Bs[128 * 64]; // 16KB
  const int K = 1024;
  const int tid = threadIdx.x;
  const int l = tid & 63;
  const int wid = tid >> 6;
  const int bid = blockIdx.x;
  const int swz = (bid & 7) * 192 + (bid >> 3); // 1536 = 8 * 192, bijective
  const bool isQ = swz < 512;
  const u16* A;
  const u16* Bw;
  int m0, n0;
  if (isQ) {
    A = xb; Bw = wqb;
    m0 = (swz >> 3) * 128;       // 64 m-tiles
    n0 = (swz & 7) * 128;        // 8 n-tiles
  } else {
    const int s = swz - 512;
    A = cb; Bw = wkvb;
    m0 = (s >> 4) * 128;         // 64 m-tiles
    n0 = (s & 15) * 128;         // 16 n-tiles (N=2048)
  }
  const int wr = wid >> 1, wc = wid & 1;
  const int r = l & 15, kg = l >> 4;
  f32x4 acc[4][4] = {};
  char* AsB = (char*)As;
  char* BsB = (char*)Bs;
  const int arow = l >> 3;
  const int agran = (l & 7) ^ arow;

  for (int kt = 0; kt < K; kt += 64) {
#pragma unroll
    for (int cc = 0; cc < 4; ++cc) {
      int c = wid + (cc << 2);
      int rowi = (c << 3) + arow;
      const char* ga = (const char*)A + ((size_t)(m0 + rowi) * K + kt) * 2 + agran * 16;
      async_copy16(AsB + c * 1024, ga);
      const char* gb = (const char*)Bw + ((size_t)(n0 + rowi) * K + kt) * 2 + agran * 16;
      async_copy16(BsB + c * 1024, gb);
    }
    __syncthreads();
#pragma unroll
    for (int half = 0; half < 2; ++half) {
      const int g = ((half << 2) + kg) ^ (r & 7);
      bf16x8 af[4], bf[4];
#pragma unroll
      for (int i = 0; i < 4; ++i) {
        af[i] = *(const bf16x8*)(AsB + (wr * 64 + i * 16 + r) * 128 + g * 16);
        bf[i] = *(const bf16x8*)(BsB + (wc * 64 + i * 16 + r) * 128 + g * 16);
      }
#pragma unroll
      for (int i = 0; i < 4; ++i)
#pragma unroll
        for (int j = 0; j < 4; ++j)
          acc[i][j] = MFMA16(af[i], bf[j], acc[i][j]);
    }
    __syncthreads();
  }

  const int colbase = n0 + wc * 64;
  const bool isV = (!isQ) && (colbase >= 1024);
  if (!isV) {
    // qknorm epilogue (Q or K): wave owns one 64-col head group per row
    u16* C = isQ ? Qb : Kb;
    const float* bias = isQ ? bq : bk;
    const float sMul = isQ ? LOG2E : 1.0f;
    float bvj[4];
#pragma unroll
    for (int j = 0; j < 4; ++j) bvj[j] = bias[colbase + j * 16 + r];
#pragma unroll
    for (int i = 0; i < 4; ++i) {
      const int row0 = m0 + wr * 64 + i * 16 + kg * 4;
#pragma unroll
      for (int jj = 0; jj < 4; ++jj) {
        float t[4];
        float s2 = 0.f;
#pragma unroll
        for (int j = 0; j < 4; ++j) {
          t[j] = acc[i][j][jj] + bvj[j];
          s2 += t[j] * t[j];
        }
        s2 += __shfl_xor(s2, 1);
        s2 += __shfl_xor(s2, 2);
        s2 += __shfl_xor(s2, 4);
        s2 += __shfl_xor(s2, 8);
        const float inv = sMul / (sqrtf(s2) + 1e-6f);
#pragma unroll
        for (int j = 0; j < 4; ++j)
          C[(size_t)(row0 + jj) * D_MODEL + colbase + j * 16 + r] = f2bf(t[j] * inv);
      }
    }
  } else {
    // V fragment store (layout doc'd at kernel header). 4-tok ushort4 per (i,j).
#pragma unroll
    for (int i = 0; i < 4; ++i) {
#pragma unroll
      for (int j = 0; j < 4; ++j) {
        const int col = colbase + j * 16 + r;      // 1024..2047
        const float bvv = bv[col - 1024];
        const int row0 = m0 + wr * 64 + i * 16 + kg * 4;
        const int dh = col & 63;
        const int bb = row0 >> 11, tok = row0 & 2047;
        const int bh2 = bb * 16 + ((col - 1024) >> 6);
        ushort4 o;
        o.x = f2bf(acc[i][j][0] + bvv);
        o.y = f2bf(acc[i][j][1] + bvv);
        o.z = f2bf(acc[i][j][2] + bvv);
        o.w = f2bf(acc[i][j][3] + bvv);
        const size_t off =
            ((size_t)(bh2 * 32 + (tok >> 6)) * 8 + ((tok >> 4) & 3) * 2 + (dh >> 5)) * 512 +
            ((dh & 31) + ((tok >> 3) & 1) * 32) * 8 + (tok & 7); // tok&7 in {0,4}: 8B aligned
        *(ushort4*)(Vfb + off) = o;
      }
    }
  }
}

// ================= output-projection NT-GEMM (f32 out) =================
__global__ __launch_bounds__(256, 3) void gemm_out(const u16* __restrict__ A,
                                                   const u16* __restrict__ Bw,
                                                   const float* __restrict__ bias,
                                                   float* __restrict__ Cout) {
  __shared__ u16 As[128 * 64];
  __shared__ u16 Bs[128 * 64];
  const int K = 1024, N = 1024;
  const int tid = threadIdx.x;
  const int l = tid & 63;
  const int wid = tid >> 6;
  const int bid = blockIdx.x;
  const int swz = (bid & 7) * 64 + (bid >> 3); // 512 = 8 * 64
  const int m0 = (swz >> 3) * 128;
  const int n0 = (swz & 7) * 128;
  const int wr = wid >> 1, wc = wid & 1;
  const int r = l & 15, kg = l >> 4;
  f32x4 acc[4][4] = {};
  char* AsB = (char*)As;
  char* BsB = (char*)Bs;
  const int arow = l >> 3;
  const int agran = (l & 7) ^ arow;

  for (int kt = 0; kt < K; kt += 64) {
#pragma unroll
    for (int cc = 0; cc < 4; ++cc) {
      int c = wid + (cc << 2);
      int rowi = (c << 3) + arow;
      const char* ga = (const char*)A + ((size_t)(m0 + rowi) * K + kt) * 2 + agran * 16;
      async_copy16(AsB + c * 1024, ga);
      const char* gb = (const char*)Bw + ((size_t)(n0 + rowi) * K + kt) * 2 + agran * 16;
      async_copy16(BsB + c * 1024, gb);
    }
    __syncthreads();
#pragma unroll
    for (int half = 0; half < 2; ++half) {
      const int g = ((half << 2) + kg) ^ (r & 7);
      bf16x8 af[4], bf[4];
#pragma unroll
      for (int i = 0; i < 4; ++i) {
        af[i] = *(const bf16x8*)(AsB + (wr * 64 + i * 16 + r) * 128 + g * 16);
        bf[i] = *(const bf16x8*)(BsB + (wc * 64 + i * 16 + r) * 128 + g * 16);
      }
#pragma unroll
      for (int i = 0; i < 4; ++i)
#pragma unroll
        for (int j = 0; j < 4; ++j)
          acc[i][j] = MFMA16(af[i], bf[j], acc[i][j]);
    }
    __syncthreads();
  }
#pragma unroll
  for (int i = 0; i < 4; ++i) {
#pragma unroll
    for (int j = 0; j < 4; ++j) {
      const int col = n0 + wc * 64 + j * 16 + r;
      const float bvv = bias[col];
      const int row0 = m0 + wr * 64 + i * 16 + kg * 4;
#pragma unroll
      for (int jj = 0; jj < 4; ++jj)
        Cout[(size_t)(row0 + jj) * N + col] = acc[i][j][jj] + bvv;
    }
  }
}

// ---------------- flash attention v9: K in LDS, V direct global->reg ----------------
// V is pre-fragmented by gemm_qkv: per (bh,t,sl,dt) a 1KB coalesced MFMA A-fragment.
// LDS holds only K (2x8KB double buffer). V-frag loads issued after QK, hidden under
// softmax; PV consumes them from registers. LDS-read pipe load halved vs v5.
#define KVB 64
#define NT (SEQ / KVB)

__global__ __launch_bounds__(256, 4) void attn_kernel(const u16* __restrict__ Q,
                                                      const u16* __restrict__ K,
                                                      const u16* __restrict__ Vf,
                                                      u16* __restrict__ O) {
  __shared__ alignas(16) u16 Ks[2][KVB * 64]; // 2 x 8KB
  const int tid = threadIdx.x;
  const int l = tid & 63;
  const int wid = tid >> 6;
  const int qg = l & 31;     // q row within wave
  const int half = l >> 5;
  // XCD-chunked grid: each XCD gets 128 consecutive swz = 8 bh values (K/V L2-resident)
  const int bid = blockIdx.x;
  const int swz = (bid & 7) * 128 + (bid >> 3);
  const int qt = swz & 15;   // 0..15
  const int bh = swz >> 4;   // 0..63
  const int b = bh >> 4, h = bh & 15;

  // ---- K stage geometry: wave handles chunks {wid, wid+4} (8 rows each)
  const int srow = l >> 3, slot = l & 7;
  const int r0 = (wid << 3) + srow;
  const int r1 = ((wid + 4) << 3) + srow;
  const int sw0 = (r0 ^ (r0 >> 3)) & 7;
  const int sw1 = (r1 ^ (r1 >> 3)) & 7;
  const u16* pK0 = K + ((size_t)(b * SEQ) + r0) * D_MODEL + h * 64 + (slot ^ sw0) * 8;
  const u16* pK1 = K + ((size_t)(b * SEQ) + r1) * D_MODEL + h * 64 + (slot ^ sw1) * 8;
  const int ldsc0 = wid * 1024, ldsc1 = (wid + 4) * 1024;
  // V fragment pointer (lane-resolved)
  const u16* pV = Vf + (size_t)bh * 32 * 8 * 512 + l * 8;

  // Q fragments (pre-scaled by log2e at GEMM): col=q=l&31, k = dc*16 + half*8 + e
  bf16x8 qf[4];
  {
    const u16* q0 = Q + ((size_t)(b * SEQ + qt * 128 + wid * 32 + qg)) * D_MODEL + h * 64 + half * 8;
#pragma unroll
    for (int dc = 0; dc < 4; ++dc) qf[dc] = *(const bf16x8*)(q0 + dc * 16);
  }
  f32x16 oacc[2] = {};
  float lrun = 0.f;

  auto stageK = [&](int bufi) {
    char* KsX = (char*)Ks[bufi];
    async_copy16(KsX + ldsc0, pK0);
    async_copy16(KsX + ldsc1, pK1);
    pK0 += (size_t)KVB * D_MODEL;
    pK1 += (size_t)KVB * D_MODEL;
  };

  // prologue: stage K(0), K(1); wait K(0) (oldest 2 of 4), barrier
  stageK(0);
  stageK(1);
  VMCNT(2);
  wg_barrier();

  for (int t = 0; t < NT; ++t) {
    const char* KsC = (const char*)Ks[t & 1];

    // S'^T[kv][q] = K·(log2e·q-hat): lane holds q=l&31, kv=(reg&3)+8*(reg>>2)+4*half (+32*t32)
    f32x16 st[2] = {};
    __builtin_amdgcn_s_setprio(1);
#pragma unroll
    for (int t32 = 0; t32 < 2; ++t32) {
      const int rowK = t32 * 32 + qg;
      const int swk = (rowK ^ (rowK >> 3)) & 7;
#pragma unroll
      for (int dc = 0; dc < 4; ++dc) {
        const int p = (dc * 2 + half) ^ swk;
        bf16x8 kf = *(const bf16x8*)(KsC + rowK * 128 + p * 16);
        st[t32] = MFMA32(kf, qf[dc], st[t32]);
      }
    }
    __builtin_amdgcn_s_setprio(0);

    // V fragment loads for this tile (8 coalesced dwordx4; land during softmax)
    bf16x8 vf[4][2];
    {
      const u16* vt = pV + (size_t)t * 4096;
#pragma unroll
      for (int sl = 0; sl < 4; ++sl) {
        vf[sl][0] = *(const bf16x8*)(vt + sl * 1024);
        vf[sl][1] = *(const bf16x8*)(vt + sl * 1024 + 512);
      }
    }

    // p = exp2(s')  (global e^1 factor cancels between numerator and denominator)
    float rs0 = 0.f, rs1 = 0.f, rs2 = 0.f, rs3 = 0.f;
#pragma unroll
    for (int t32 = 0; t32 < 2; ++t32)
#pragma unroll
      for (int rr = 0; rr < 16; rr += 4) {
        float p0 = __builtin_amdgcn_exp2f(st[t32][rr + 0]);
        float p1 = __builtin_amdgcn_exp2f(st[t32][rr + 1]);
        float p2 = __builtin_amdgcn_exp2f(st[t32][rr + 2]);
        float p3 = __builtin_amdgcn_exp2f(st[t32][rr + 3]);
        st[t32][rr + 0] = p0; st[t32][rr + 1] = p1;
        st[t32][rr + 2] = p2; st[t32][rr + 3] = p3;
        rs0 += p0; rs1 += p1; rs2 += p2; rs3 += p3;
      }
    lrun += (rs0 + rs1) + (rs2 + rs3);

    // all waves done reading Ks[t&1] -> safe to overwrite with K(t+2)
    wg_barrier();
    if (t + 2 < NT) stageK(t & 1);

    // PV: O^T[dh][q] += V^T[dh][kv] * P[q][kv]   (vf from registers)
#pragma unroll
    for (int t32 = 0; t32 < 2; ++t32) {
#pragma unroll
      for (int cc = 0; cc < 2; ++cc) {
        const int base = cc * 8;
        u32 wA = cvtpk_bf16(st[t32][base + 0], st[t32][base + 1]);
        u32 wB = cvtpk_bf16(st[t32][base + 2], st[t32][base + 3]);
        u32 wC = cvtpk_bf16(st[t32][base + 4], st[t32][base + 5]);
        u32 wD = cvtpk_bf16(st[t32][base + 6], st[t32][base + 7]);
        permswap(wA, wC);
        permswap(wB, wD);
        u32x4 pw = {wA, wB, wC, wD};
        bf16x8 pf = __builtin_bit_cast(bf16x8, pw);
        const int sl = t32 * 2 + cc;
        __builtin_amdgcn_s_setprio(1);
        oacc[0] = MFMA32(vf[sl][0], pf, oacc[0]);
        oacc[1] = MFMA32(vf[sl][1], pf, oacc[1]);
        __builtin_amdgcn_s_setprio(0);
      }
    }
    // this wave's K(t+1) landed (only K(t+2)'s 2 loads may remain); all-waves barrier
    VMCNT(2);
    wg_barrier();
  }

  // epilogue: denom = own-half sum + other-half sum; pack pairs, u32 stores
  lrun += __shfl_xor(lrun, 32);
  const float inv = 1.0f / lrun;
  u32* orow = (u32*)(O + ((size_t)(b * SEQ + qt * 128 + wid * 32 + qg)) * D_MODEL + h * 64);
#pragma unroll
  for (int dt = 0; dt < 2; ++dt)
#pragma unroll
    for (int w = 0; w < 8; ++w) {
      const int dh = dt * 32 + (w & 1) * 2 + 8 * (w >> 1) + 4 * half;
      u32 pk = cvtpk_bf16(oacc[dt][2 * w] * inv, oacc[dt][2 * w + 1] * inv);
      orow[dh >> 1] = pk;
    }
}

// ---------------- launch ----------------
extern "C" void kernel_launch(void* const* d_in, const int* in_sizes, int n_in,
                              void* d_out, int out_size, void* d_ws, size_t ws_size,
                              hipStream_t stream) {
  const float* x   = (const float*)d_in[0];
  const float* ctx = (const float*)d_in[1];
  const float* Wq  = (const float*)d_in[2];
  const float* bq  = (const float*)d_in[3];
  const float* Wk  = (const float*)d_in[4];
  const float* bk  = (const float*)d_in[5];
  const float* Wv  = (const float*)d_in[6];
  const float* bv  = (const float*)d_in[7];
  const float* Wo  = (const float*)d_in[8];
  const float* bo  = (const float*)d_in[9];
  float* out = (float*)d_out;

  const size_t NTOK = (size_t)MTOT * D_MODEL; // 8M elems
  const size_t WSZ = (size_t)D_MODEL * D_MODEL;
  u16* xb  = (u16*)d_ws;       // x bf16; later reused as attention output
  u16* cb  = xb + NTOK;
  u16* wqb = cb + NTOK;
  u16* wkb = wqb + WSZ;        // wk,wv adjacent -> fused [K|V] GEMM B-panel
  u16* wvb = wkb + WSZ;
  u16* wob = wvb + WSZ;
  u16* Qb  = wob + WSZ;
  u16* Kb  = Qb + NTOK;
  u16* Vfb = Kb + NTOK;        // V in pre-fragmented MFMA A-operand layout
  (void)in_sizes; (void)n_in; (void)out_size; (void)ws_size;

  dim3 blk(256);
  cvt_all<<<2048, blk, 0, stream>>>(x, ctx, Wq, Wk, Wv, Wo, xb, cb, wqb, wkb, wvb, wob);

  gemm_qkv<<<1536, blk, 0, stream>>>(xb, cb, wqb, wkb, bq, bk, bv, Qb, Kb, Vfb);

  attn_kernel<<<1024, blk, 0, stream>>>(Qb, Kb, Vfb, xb);

  gemm_out<<<512, blk, 0, stream>>>(xb, wob, bo, out);
}

// Round 11
// 188.670 us; speedup vs baseline: 1.0259x; 1.0259x over previous
//
#include <hip/hip_runtime.h>

typedef unsigned short u16;
typedef unsigned int u32;
typedef __attribute__((ext_vector_type(8))) short bf16x8;
typedef __attribute__((ext_vector_type(4))) float f32x4;
typedef __attribute__((ext_vector_type(16))) float f32x16;
typedef __attribute__((ext_vector_type(4))) u32 u32x4;

#define D_MODEL 1024
#define NHEAD 16
#define DHEAD 64
#define SEQ 2048
#define BATCH 4
#define MTOT (BATCH * SEQ) /* 8192 */
#define LOG2E 1.4426950408889634f

#define MFMA16(A, B, C) __builtin_amdgcn_mfma_f32_16x16x32_bf16((A), (B), (C), 0, 0, 0)
#define MFMA32(A, B, C) __builtin_amdgcn_mfma_f32_32x32x16_bf16((A), (B), (C), 0, 0, 0)

__device__ __forceinline__ u16 f2bf(float f) {
  u32 u = __builtin_bit_cast(u32, f);
  u = (u + 0x7FFFu + ((u >> 16) & 1u)) >> 16;
  return (u16)u;
}

// async global->LDS, 16B per lane. lds must be wave-uniform; g is per-lane.
__device__ __forceinline__ void async_copy16(void* lds, const void* g) {
  __builtin_amdgcn_global_load_lds(
      (const __attribute__((address_space(1))) u32*)g,
      (__attribute__((address_space(3))) u32*)lds, 16, 0, 0);
}

__device__ __forceinline__ u32 cvtpk_bf16(float lo, float hi) {
  u32 r;
  asm("v_cvt_pk_bf16_f32 %0, %1, %2" : "=v"(r) : "v"(lo), "v"(hi));
  return r;
}
// swaps a.hi32lanes <-> b.lo32lanes
__device__ __forceinline__ void permswap(u32& a, u32& b) {
  asm("v_permlane32_swap_b32 %0, %1" : "+v"(a), "+v"(b));
}

// raw workgroup barrier WITHOUT vmcnt drain (T4); memory-clobbered + sched-fenced
__device__ __forceinline__ void wg_barrier() {
  __builtin_amdgcn_sched_barrier(0);
  asm volatile("s_barrier" ::: "memory");
  __builtin_amdgcn_sched_barrier(0);
}
#define VMCNT(N) asm volatile("s_waitcnt vmcnt(" #N ")" ::: "memory")

// ---------------- fp32 -> bf16 convert (all six tensors, one launch) ----------------
__global__ void cvt_all(const float* __restrict__ x, const float* __restrict__ ctx,
                        const float* __restrict__ Wq, const float* __restrict__ Wk,
                        const float* __restrict__ Wv, const float* __restrict__ Wo,
                        u16* __restrict__ xb, u16* __restrict__ cb,
                        u16* __restrict__ wqb, u16* __restrict__ wkb,
                        u16* __restrict__ wvb, u16* __restrict__ wob) {
  const int NX = 1 << 21;                 // x / ctx in float4 units (8M/4)
  const int NW = 1 << 18;                 // each weight in float4 units (1M/4)
  const int total = 2 * NX + 4 * NW;
  int i = blockIdx.x * blockDim.x + threadIdx.x;
  const int st = gridDim.x * blockDim.x;
  for (; i < total; i += st) {
    const float* s; u16* d; int j;
    if (i < NX)            { s = x;   d = xb;  j = i; }
    else if (i < 2 * NX)   { s = ctx; d = cb;  j = i - NX; }
    else {
      int k = i - 2 * NX;
      int wi = k >> 18;
      j = k & (NW - 1);
      s = (wi == 0) ? Wq : (wi == 1) ? Wk : (wi == 2) ? Wv : Wo;
      d = (wi == 0) ? wqb : (wi == 1) ? wkb : (wi == 2) ? wvb : wob;
    }
    float4 v = ((const float4*)s)[j];
    ushort4 o;
    o.x = f2bf(v.x); o.y = f2bf(v.y); o.z = f2bf(v.z); o.w = f2bf(v.w);
    ((ushort4*)d)[j] = o;
  }
}

// ================= fused QKV NT-GEMM =================
// grid 1536: swz<512 -> Q = x·Wq^T (+bq, qknorm, *log2e) -> Qb
//            swz>=512 -> [K|V] = ctx·[Wk;Wv]^T; cols<1024: K (+bk, qknorm) -> Kb
//                                               cols>=1024: V (+bv, transposed) -> Vtb
__global__ __launch_bounds__(256, 3) void gemm_qkv(
    const u16* __restrict__ xb, const u16* __restrict__ cb,
    const u16* __restrict__ wqb, const u16* __restrict__ wkvb,
    const float* __restrict__ bq, const float* __restrict__ bk,
    const float* __restrict__ bv,
    u16* __restrict__ Qb, u16* __restrict__ Kb, u16* __restrict__ Vtb) {
  __shared__ u16 As[128 * 64]; // 16KB, rows 128B, granule-swizzled g^=(row&7)
  __shared__ u16 Bs[128 * 64]; // 16KB
  const int K = 1024;
  const int tid = threadIdx.x;
  const int l = tid & 63;
  const int wid = tid >> 6;
  const int bid = blockIdx.x;
  const int swz = (bid & 7) * 192 + (bid >> 3); // 1536 = 8 * 192, bijective
  const bool isQ = swz < 512;
  const u16* A;
  const u16* Bw;
  int m0, n0;
  if (isQ) {
    A = xb; Bw = wqb;
    m0 = (swz >> 3) * 128;       // 64 m-tiles
    n0 = (swz & 7) * 128;        // 8 n-tiles
  } else {
    const int s = swz - 512;
    A = cb; Bw = wkvb;
    m0 = (s >> 4) * 128;         // 64 m-tiles
    n0 = (s & 15) * 128;         // 16 n-tiles (N=2048)
  }
  const int wr = wid >> 1, wc = wid & 1;
  const int r = l & 15, kg = l >> 4;
  f32x4 acc[4][4] = {};
  char* AsB = (char*)As;
  char* BsB = (char*)Bs;
  const int arow = l >> 3;
  const int agran = (l & 7) ^ arow;

  for (int kt = 0; kt < K; kt += 64) {
#pragma unroll
    for (int cc = 0; cc < 4; ++cc) {
      int c = wid + (cc << 2);
      int rowi = (c << 3) + arow;
      const char* ga = (const char*)A + ((size_t)(m0 + rowi) * K + kt) * 2 + agran * 16;
      async_copy16(AsB + c * 1024, ga);
      const char* gb = (const char*)Bw + ((size_t)(n0 + rowi) * K + kt) * 2 + agran * 16;
      async_copy16(BsB + c * 1024, gb);
    }
    __syncthreads();
#pragma unroll
    for (int half = 0; half < 2; ++half) {
      const int g = ((half << 2) + kg) ^ (r & 7);
      bf16x8 af[4], bf[4];
#pragma unroll
      for (int i = 0; i < 4; ++i) {
        af[i] = *(const bf16x8*)(AsB + (wr * 64 + i * 16 + r) * 128 + g * 16);
        bf[i] = *(const bf16x8*)(BsB + (wc * 64 + i * 16 + r) * 128 + g * 16);
      }
#pragma unroll
      for (int i = 0; i < 4; ++i)
#pragma unroll
        for (int j = 0; j < 4; ++j)
          acc[i][j] = MFMA16(af[i], bf[j], acc[i][j]);
    }
    __syncthreads();
  }

  const int colbase = n0 + wc * 64;
  const bool isV = (!isQ) && (colbase >= 1024);
  if (!isV) {
    // qknorm epilogue (Q or K): wave owns one 64-col head group per row
    u16* C = isQ ? Qb : Kb;
    const float* bias = isQ ? bq : bk;
    const float sMul = isQ ? LOG2E : 1.0f;
    float bvj[4];
#pragma unroll
    for (int j = 0; j < 4; ++j) bvj[j] = bias[colbase + j * 16 + r];
#pragma unroll
    for (int i = 0; i < 4; ++i) {
      const int row0 = m0 + wr * 64 + i * 16 + kg * 4;
#pragma unroll
      for (int jj = 0; jj < 4; ++jj) {
        float t[4];
        float s2 = 0.f;
#pragma unroll
        for (int j = 0; j < 4; ++j) {
          t[j] = acc[i][j][jj] + bvj[j];
          s2 += t[j] * t[j];
        }
        s2 += __shfl_xor(s2, 1);
        s2 += __shfl_xor(s2, 2);
        s2 += __shfl_xor(s2, 4);
        s2 += __shfl_xor(s2, 8);
        const float inv = sMul / (sqrtf(s2) + 1e-6f);
#pragma unroll
        for (int j = 0; j < 4; ++j)
          C[(size_t)(row0 + jj) * D_MODEL + colbase + j * 16 + r] = f2bf(t[j] * inv);
      }
    }
  } else {
    // V transposed store: Vt[(b*16+h)*64 + dh][tok], 4 consecutive tok per lane
#pragma unroll
    for (int i = 0; i < 4; ++i) {
#pragma unroll
      for (int j = 0; j < 4; ++j) {
        const int col = colbase + j * 16 + r;      // 1024..2047
        const float bvv = bv[col - 1024];
        const int row0 = m0 + wr * 64 + i * 16 + kg * 4;
        const int hh = (col - 1024) >> 6, dh = col & 63;
        const int bb = row0 >> 11, tok = row0 & 2047;
        ushort4 o;
        o.x = f2bf(acc[i][j][0] + bvv);
        o.y = f2bf(acc[i][j][1] + bvv);
        o.z = f2bf(acc[i][j][2] + bvv);
        o.w = f2bf(acc[i][j][3] + bvv);
        *(ushort4*)(Vtb + ((size_t)((bb * 16 + hh) * 64 + dh) * SEQ + tok)) = o;
      }
    }
  }
}

// ================= output-projection NT-GEMM (f32 out) =================
__global__ __launch_bounds__(256, 3) void gemm_out(const u16* __restrict__ A,
                                                   const u16* __restrict__ Bw,
                                                   const float* __restrict__ bias,
                                                   float* __restrict__ Cout) {
  __shared__ u16 As[128 * 64];
  __shared__ u16 Bs[128 * 64];
  const int K = 1024, N = 1024;
  const int tid = threadIdx.x;
  const int l = tid & 63;
  const int wid = tid >> 6;
  const int bid = blockIdx.x;
  const int swz = (bid & 7) * 64 + (bid >> 3); // 512 = 8 * 64
  const int m0 = (swz >> 3) * 128;
  const int n0 = (swz & 7) * 128;
  const int wr = wid >> 1, wc = wid & 1;
  const int r = l & 15, kg = l >> 4;
  f32x4 acc[4][4] = {};
  char* AsB = (char*)As;
  char* BsB = (char*)Bs;
  const int arow = l >> 3;
  const int agran = (l & 7) ^ arow;

  for (int kt = 0; kt < K; kt += 64) {
#pragma unroll
    for (int cc = 0; cc < 4; ++cc) {
      int c = wid + (cc << 2);
      int rowi = (c << 3) + arow;
      const char* ga = (const char*)A + ((size_t)(m0 + rowi) * K + kt) * 2 + agran * 16;
      async_copy16(AsB + c * 1024, ga);
      const char* gb = (const char*)Bw + ((size_t)(n0 + rowi) * K + kt) * 2 + agran * 16;
      async_copy16(BsB + c * 1024, gb);
    }
    __syncthreads();
#pragma unroll
    for (int half = 0; half < 2; ++half) {
      const int g = ((half << 2) + kg) ^ (r & 7);
      bf16x8 af[4], bf[4];
#pragma unroll
      for (int i = 0; i < 4; ++i) {
        af[i] = *(const bf16x8*)(AsB + (wr * 64 + i * 16 + r) * 128 + g * 16);
        bf[i] = *(const bf16x8*)(BsB + (wc * 64 + i * 16 + r) * 128 + g * 16);
      }
#pragma unroll
      for (int i = 0; i < 4; ++i)
#pragma unroll
        for (int j = 0; j < 4; ++j)
          acc[i][j] = MFMA16(af[i], bf[j], acc[i][j]);
    }
    __syncthreads();
  }
#pragma unroll
  for (int i = 0; i < 4; ++i) {
#pragma unroll
    for (int j = 0; j < 4; ++j) {
      const int col = n0 + wc * 64 + j * 16 + r;
      const float bvv = bias[col];
      const int row0 = m0 + wr * 64 + i * 16 + kg * 4;
#pragma unroll
      for (int jj = 0; jj < 4; ++jj)
        Cout[(size_t)(row0 + jj) * N + col] = acc[i][j][jj] + bvv;
    }
  }
}

// ---------------- flash attention v11: v9 pipeline + denominator via ones-MFMA ----------------
// K,V in LDS (round-9 best structure: KVB=64, 4 blocks/CU, counted vmcnt, raw barriers).
// NEW: softmax denominator computed as ones-row MFMA over the bf16 P fragments
// (4 extra MFMA32/tile) replacing 32 VALU adds/tile + the epilogue shuffle; denom is
// now consistent with the bf16 numerator P.
#define KVB 64
#define NT (SEQ / KVB)

__global__ __launch_bounds__(256, 4) void attn_kernel(const u16* __restrict__ Q,
                                                      const u16* __restrict__ K,
                                                      const u16* __restrict__ Vt,
                                                      u16* __restrict__ O) {
  __shared__ alignas(16) u16 Ks[2][KVB * 64]; // 2 x 8KB
  __shared__ alignas(16) u16 Vs[2][64 * KVB]; // 2 x 8KB
  const int tid = threadIdx.x;
  const int l = tid & 63;
  const int wid = tid >> 6;
  const int qg = l & 31;     // q row within wave
  const int half = l >> 5;
  // XCD-chunked grid: each XCD gets 128 consecutive swz = 8 bh values (K/V L2-resident)
  const int bid = blockIdx.x;
  const int swz = (bid & 7) * 128 + (bid >> 3);
  const int qt = swz & 15;   // 0..15
  const int bh = swz >> 4;   // 0..63
  const int b = bh >> 4, h = bh & 15;

  // ---- stage geometry: wave handles K chunks {wid, wid+4} and V chunks {wid, wid+4}
  const int srow = l >> 3, slot = l & 7;
  const int r0 = (wid << 3) + srow;
  const int r1 = ((wid + 4) << 3) + srow;
  const int sw0 = (r0 ^ (r0 >> 3)) & 7;
  const int sw1 = (r1 ^ (r1 >> 3)) & 7;
  const u16* pK0 = K + ((size_t)(b * SEQ) + r0) * D_MODEL + h * 64 + (slot ^ sw0) * 8;
  const u16* pK1 = K + ((size_t)(b * SEQ) + r1) * D_MODEL + h * 64 + (slot ^ sw1) * 8;
  const u16* pV0 = Vt + ((size_t)(bh * 64) + r0) * SEQ + (slot ^ sw0) * 8;
  const u16* pV1 = Vt + ((size_t)(bh * 64) + r1) * SEQ + (slot ^ sw1) * 8;
  const int ldsc0 = wid * 1024, ldsc1 = (wid + 4) * 1024;

  // Q fragments (pre-scaled by log2e at GEMM): col=q=l&31, k = dc*16 + half*8 + e
  bf16x8 qf[4];
  {
    const u16* q0 = Q + ((size_t)(b * SEQ + qt * 128 + wid * 32 + qg)) * D_MODEL + h * 64 + half * 8;
#pragma unroll
    for (int dc = 0; dc < 4; ++dc) qf[dc] = *(const bf16x8*)(q0 + dc * 16);
  }
  // ones A-fragment (bf16 1.0 x8) for the denominator MFMA
  const u32x4 onesw = {0x3F803F80u, 0x3F803F80u, 0x3F803F80u, 0x3F803F80u};
  const bf16x8 ones = __builtin_bit_cast(bf16x8, onesw);

  f32x16 oacc[2] = {};
  f32x16 sumacc = {};

  auto stage = [&](int bufi) {
    char* KsX = (char*)Ks[bufi];
    char* VsX = (char*)Vs[bufi];
    async_copy16(KsX + ldsc0, pK0);
    async_copy16(KsX + ldsc1, pK1);
    async_copy16(VsX + ldsc0, pV0);
    async_copy16(VsX + ldsc1, pV1);
    pK0 += (size_t)KVB * D_MODEL;
    pK1 += (size_t)KVB * D_MODEL;
    pV0 += KVB;
    pV1 += KVB;
  };

  auto process = [&](int bufi) {
    const char* KsC = (const char*)Ks[bufi];
    const char* VsC = (const char*)Vs[bufi];
    // S'^T[kv][q] = K·(log2e·q-hat): lane holds q=l&31, kv=(reg&3)+8*(reg>>2)+4*half (+32*t32)
    f32x16 st[2] = {};
    __builtin_amdgcn_s_setprio(1);
#pragma unroll
    for (int t32 = 0; t32 < 2; ++t32) {
      const int rowK = t32 * 32 + qg;
      const int swk = (rowK ^ (rowK >> 3)) & 7;
#pragma unroll
      for (int dc = 0; dc < 4; ++dc) {
        const int p = (dc * 2 + half) ^ swk;
        bf16x8 kf = *(const bf16x8*)(KsC + rowK * 128 + p * 16);
        st[t32] = MFMA32(kf, qf[dc], st[t32]);
      }
    }
    __builtin_amdgcn_s_setprio(0);

    // p = exp2(s')  (global e^1 factor cancels between numerator and denominator)
#pragma unroll
    for (int t32 = 0; t32 < 2; ++t32)
#pragma unroll
      for (int rr = 0; rr < 16; rr += 4) {
        st[t32][rr + 0] = __builtin_amdgcn_exp2f(st[t32][rr + 0]);
        st[t32][rr + 1] = __builtin_amdgcn_exp2f(st[t32][rr + 1]);
        st[t32][rr + 2] = __builtin_amdgcn_exp2f(st[t32][rr + 2]);
        st[t32][rr + 3] = __builtin_amdgcn_exp2f(st[t32][rr + 3]);
      }

    // PV: O^T[dh][q] += V^T[dh][kv] * P[q][kv]; denom: sumacc += ones * P
#pragma unroll
    for (int t32 = 0; t32 < 2; ++t32) {
#pragma unroll
      for (int cc = 0; cc < 2; ++cc) {
        const int base = cc * 8;
        u32 wA = cvtpk_bf16(st[t32][base + 0], st[t32][base + 1]);
        u32 wB = cvtpk_bf16(st[t32][base + 2], st[t32][base + 3]);
        u32 wC = cvtpk_bf16(st[t32][base + 4], st[t32][base + 5]);
        u32 wD = cvtpk_bf16(st[t32][base + 6], st[t32][base + 7]);
        permswap(wA, wC);
        permswap(wB, wD);
        u32x4 pw = {wA, wB, wC, wD};
        bf16x8 pf = __builtin_bit_cast(bf16x8, pw);
        const int qw = ((t32 * 2 + cc) << 1) + half;
        __builtin_amdgcn_s_setprio(1);
#pragma unroll
        for (int dt = 0; dt < 2; ++dt) {
          const int rowV = dt * 32 + qg;
          const int pp = qw ^ ((rowV ^ (rowV >> 3)) & 7);
          bf16x8 vf = *(const bf16x8*)(VsC + rowV * 128 + pp * 16);
          oacc[dt] = MFMA32(vf, pf, oacc[dt]);
        }
        sumacc = MFMA32(ones, pf, sumacc);
        __builtin_amdgcn_s_setprio(0);
      }
    }
  };

  // prologue: stage tiles 0 and 1, one full drain (also covers Q-frag loads)
  stage(0);
  stage(1);
  VMCNT(0);
  wg_barrier();

  // main loop: tiles 0 .. NT-2; stage(t+2) guarded
  for (int t = 0; t < NT - 1; ++t) {
    VMCNT(4);               // stage(t) complete; stage(t+1) stays in flight
    wg_barrier();           // all waves see tile t (no drain)
    process(t & 1);
    wg_barrier();           // all waves done reading buf (t&1)
    if (t + 2 < NT) stage(t & 1);
  }
  // peel final tile: nothing left in flight except its stage -> full drain
  VMCNT(0);
  wg_barrier();
  process((NT - 1) & 1);

  // epilogue: denom = sumacc[0] (all rows of the ones-MFMA are the row-sum; covers
  // all 64 kv per tile and both lane halves); pack pairs, u32 stores
  const float inv = 1.0f / sumacc[0];
  u32* orow = (u32*)(O + ((size_t)(b * SEQ + qt * 128 + wid * 32 + qg)) * D_MODEL + h * 64);
#pragma unroll
  for (int dt = 0; dt < 2; ++dt)
#pragma unroll
    for (int w = 0; w < 8; ++w) {
      const int dh = dt * 32 + (w & 1) * 2 + 8 * (w >> 1) + 4 * half;
      u32 pk = cvtpk_bf16(oacc[dt][2 * w] * inv, oacc[dt][2 * w + 1] * inv);
      orow[dh >> 1] = pk;
    }
}

// ---------------- launch ----------------
extern "C" void kernel_launch(void* const* d_in, const int* in_sizes, int n_in,
                              void* d_out, int out_size, void* d_ws, size_t ws_size,
                              hipStream_t stream) {
  const float* x   = (const float*)d_in[0];
  const float* ctx = (const float*)d_in[1];
  const float* Wq  = (const float*)d_in[2];
  const float* bq  = (const float*)d_in[3];
  const float* Wk  = (const float*)d_in[4];
  const float* bk  = (const float*)d_in[5];
  const float* Wv  = (const float*)d_in[6];
  const float* bv  = (const float*)d_in[7];
  const float* Wo  = (const float*)d_in[8];
  const float* bo  = (const float*)d_in[9];
  float* out = (float*)d_out;

  const size_t NTOK = (size_t)MTOT * D_MODEL; // 8M elems
  const size_t WSZ = (size_t)D_MODEL * D_MODEL;
  u16* xb  = (u16*)d_ws;       // x bf16; later reused as attention output
  u16* cb  = xb + NTOK;
  u16* wqb = cb + NTOK;
  u16* wkb = wqb + WSZ;        // wk,wv adjacent -> fused [K|V] GEMM B-panel
  u16* wvb = wkb + WSZ;
  u16* wob = wvb + WSZ;
  u16* Qb  = wob + WSZ;
  u16* Kb  = Qb + NTOK;
  u16* Vtb = Kb + NTOK;        // [b*16+h][dh][tok]
  (void)in_sizes; (void)n_in; (void)out_size; (void)ws_size;

  dim3 blk(256);
  cvt_all<<<2048, blk, 0, stream>>>(x, ctx, Wq, Wk, Wv, Wo, xb, cb, wqb, wkb, wvb, wob);

  gemm_qkv<<<1536, blk, 0, stream>>>(xb, cb, wqb, wkb, bq, bk, bv, Qb, Kb, Vtb);

  attn_kernel<<<1024, blk, 0, stream>>>(Qb, Kb, Vtb, xb);

  gemm_out<<<512, blk, 0, stream>>>(xb, wob, bo, out);
}

// Round 12
// 177.378 us; speedup vs baseline: 1.0912x; 1.0637x over previous
//
#include <hip/hip_runtime.h>

typedef unsigned short u16;
typedef unsigned int u32;
typedef __attribute__((ext_vector_type(8))) short bf16x8;
typedef __attribute__((ext_vector_type(4))) float f32x4;
typedef __attribute__((ext_vector_type(16))) float f32x16;
typedef __attribute__((ext_vector_type(4))) u32 u32x4;

#define D_MODEL 1024
#define NHEAD 16
#define DHEAD 64
#define SEQ 2048
#define BATCH 4
#define MTOT (BATCH * SEQ) /* 8192 */
#define LOG2E 1.4426950408889634f

#define MFMA16(A, B, C) __builtin_amdgcn_mfma_f32_16x16x32_bf16((A), (B), (C), 0, 0, 0)
#define MFMA32(A, B, C) __builtin_amdgcn_mfma_f32_32x32x16_bf16((A), (B), (C), 0, 0, 0)

__device__ __forceinline__ u16 f2bf(float f) {
  u32 u = __builtin_bit_cast(u32, f);
  u = (u + 0x7FFFu + ((u >> 16) & 1u)) >> 16;
  return (u16)u;
}

// async global->LDS, 16B per lane. lds must be wave-uniform; g is per-lane.
__device__ __forceinline__ void async_copy16(void* lds, const void* g) {
  __builtin_amdgcn_global_load_lds(
      (const __attribute__((address_space(1))) u32*)g,
      (__attribute__((address_space(3))) u32*)lds, 16, 0, 0);
}

__device__ __forceinline__ u32 cvtpk_bf16(float lo, float hi) {
  u32 r;
  asm("v_cvt_pk_bf16_f32 %0, %1, %2" : "=v"(r) : "v"(lo), "v"(hi));
  return r;
}
// swaps a.hi32lanes <-> b.lo32lanes
__device__ __forceinline__ void permswap(u32& a, u32& b) {
  asm("v_permlane32_swap_b32 %0, %1" : "+v"(a), "+v"(b));
}

// raw workgroup barrier WITHOUT vmcnt drain (T4); memory-clobbered + sched-fenced
__device__ __forceinline__ void wg_barrier() {
  __builtin_amdgcn_sched_barrier(0);
  asm volatile("s_barrier" ::: "memory");
  __builtin_amdgcn_sched_barrier(0);
}
#define VMCNT(N) asm volatile("s_waitcnt vmcnt(" #N ")" ::: "memory")

// ---------------- fp32 -> bf16 convert (all six tensors, one launch) ----------------
__global__ void cvt_all(const float* __restrict__ x, const float* __restrict__ ctx,
                        const float* __restrict__ Wq, const float* __restrict__ Wk,
                        const float* __restrict__ Wv, const float* __restrict__ Wo,
                        u16* __restrict__ xb, u16* __restrict__ cb,
                        u16* __restrict__ wqb, u16* __restrict__ wkb,
                        u16* __restrict__ wvb, u16* __restrict__ wob) {
  const int NX = 1 << 21;                 // x / ctx in float4 units (8M/4)
  const int NW = 1 << 18;                 // each weight in float4 units (1M/4)
  const int total = 2 * NX + 4 * NW;
  int i = blockIdx.x * blockDim.x + threadIdx.x;
  const int st = gridDim.x * blockDim.x;
  for (; i < total; i += st) {
    const float* s; u16* d; int j;
    if (i < NX)            { s = x;   d = xb;  j = i; }
    else if (i < 2 * NX)   { s = ctx; d = cb;  j = i - NX; }
    else {
      int k = i - 2 * NX;
      int wi = k >> 18;
      j = k & (NW - 1);
      s = (wi == 0) ? Wq : (wi == 1) ? Wk : (wi == 2) ? Wv : Wo;
      d = (wi == 0) ? wqb : (wi == 1) ? wkb : (wi == 2) ? wvb : wob;
    }
    float4 v = ((const float4*)s)[j];
    ushort4 o;
    o.x = f2bf(v.x); o.y = f2bf(v.y); o.z = f2bf(v.z); o.w = f2bf(v.w);
    ((ushort4*)d)[j] = o;
  }
}

// ================= fused QKV NT-GEMM =================
// grid 1536: swz<512 -> Q = x·Wq^T (+bq, qknorm, *log2e) -> Qb
//            swz>=512 -> [K|V] = ctx·[Wk;Wv]^T; cols<1024: K (+bk, qknorm) -> Kb
//                                               cols>=1024: V (+bv, transposed) -> Vtb
__global__ __launch_bounds__(256, 3) void gemm_qkv(
    const u16* __restrict__ xb, const u16* __restrict__ cb,
    const u16* __restrict__ wqb, const u16* __restrict__ wkvb,
    const float* __restrict__ bq, const float* __restrict__ bk,
    const float* __restrict__ bv,
    u16* __restrict__ Qb, u16* __restrict__ Kb, u16* __restrict__ Vtb) {
  __shared__ u16 As[128 * 64]; // 16KB, rows 128B, granule-swizzled g^=(row&7)
  __shared__ u16 Bs[128 * 64]; // 16KB
  const int K = 1024;
  const int tid = threadIdx.x;
  const int l = tid & 63;
  const int wid = tid >> 6;
  const int bid = blockIdx.x;
  const int swz = (bid & 7) * 192 + (bid >> 3); // 1536 = 8 * 192, bijective
  const bool isQ = swz < 512;
  const u16* A;
  const u16* Bw;
  int m0, n0;
  if (isQ) {
    A = xb; Bw = wqb;
    m0 = (swz >> 3) * 128;       // 64 m-tiles
    n0 = (swz & 7) * 128;        // 8 n-tiles
  } else {
    const int s = swz - 512;
    A = cb; Bw = wkvb;
    m0 = (s >> 4) * 128;         // 64 m-tiles
    n0 = (s & 15) * 128;         // 16 n-tiles (N=2048)
  }
  const int wr = wid >> 1, wc = wid & 1;
  const int r = l & 15, kg = l >> 4;
  f32x4 acc[4][4] = {};
  char* AsB = (char*)As;
  char* BsB = (char*)Bs;
  const int arow = l >> 3;
  const int agran = (l & 7) ^ arow;

  for (int kt = 0; kt < K; kt += 64) {
#pragma unroll
    for (int cc = 0; cc < 4; ++cc) {
      int c = wid + (cc << 2);
      int rowi = (c << 3) + arow;
      const char* ga = (const char*)A + ((size_t)(m0 + rowi) * K + kt) * 2 + agran * 16;
      async_copy16(AsB + c * 1024, ga);
      const char* gb = (const char*)Bw + ((size_t)(n0 + rowi) * K + kt) * 2 + agran * 16;
      async_copy16(BsB + c * 1024, gb);
    }
    __syncthreads();
#pragma unroll
    for (int half = 0; half < 2; ++half) {
      const int g = ((half << 2) + kg) ^ (r & 7);
      bf16x8 af[4], bf[4];
#pragma unroll
      for (int i = 0; i < 4; ++i) {
        af[i] = *(const bf16x8*)(AsB + (wr * 64 + i * 16 + r) * 128 + g * 16);
        bf[i] = *(const bf16x8*)(BsB + (wc * 64 + i * 16 + r) * 128 + g * 16);
      }
#pragma unroll
      for (int i = 0; i < 4; ++i)
#pragma unroll
        for (int j = 0; j < 4; ++j)
          acc[i][j] = MFMA16(af[i], bf[j], acc[i][j]);
    }
    __syncthreads();
  }

  const int colbase = n0 + wc * 64;
  const bool isV = (!isQ) && (colbase >= 1024);
  if (!isV) {
    // qknorm epilogue (Q or K): wave owns one 64-col head group per row
    u16* C = isQ ? Qb : Kb;
    const float* bias = isQ ? bq : bk;
    const float sMul = isQ ? LOG2E : 1.0f;
    float bvj[4];
#pragma unroll
    for (int j = 0; j < 4; ++j) bvj[j] = bias[colbase + j * 16 + r];
#pragma unroll
    for (int i = 0; i < 4; ++i) {
      const int row0 = m0 + wr * 64 + i * 16 + kg * 4;
#pragma unroll
      for (int jj = 0; jj < 4; ++jj) {
        float t[4];
        float s2 = 0.f;
#pragma unroll
        for (int j = 0; j < 4; ++j) {
          t[j] = acc[i][j][jj] + bvj[j];
          s2 += t[j] * t[j];
        }
        s2 += __shfl_xor(s2, 1);
        s2 += __shfl_xor(s2, 2);
        s2 += __shfl_xor(s2, 4);
        s2 += __shfl_xor(s2, 8);
        const float inv = sMul / (sqrtf(s2) + 1e-6f);
#pragma unroll
        for (int j = 0; j < 4; ++j)
          C[(size_t)(row0 + jj) * D_MODEL + colbase + j * 16 + r] = f2bf(t[j] * inv);
      }
    }
  } else {
    // V transposed store: Vt[(b*16+h)*64 + dh][tok], 4 consecutive tok per lane
#pragma unroll
    for (int i = 0; i < 4; ++i) {
#pragma unroll
      for (int j = 0; j < 4; ++j) {
        const int col = colbase + j * 16 + r;      // 1024..2047
        const float bvv = bv[col - 1024];
        const int row0 = m0 + wr * 64 + i * 16 + kg * 4;
        const int hh = (col - 1024) >> 6, dh = col & 63;
        const int bb = row0 >> 11, tok = row0 & 2047;
        ushort4 o;
        o.x = f2bf(acc[i][j][0] + bvv);
        o.y = f2bf(acc[i][j][1] + bvv);
        o.z = f2bf(acc[i][j][2] + bvv);
        o.w = f2bf(acc[i][j][3] + bvv);
        *(ushort4*)(Vtb + ((size_t)((bb * 16 + hh) * 64 + dh) * SEQ + tok)) = o;
      }
    }
  }
}

// ================= output-projection NT-GEMM (f32 out) =================
__global__ __launch_bounds__(256, 3) void gemm_out(const u16* __restrict__ A,
                                                   const u16* __restrict__ Bw,
                                                   const float* __restrict__ bias,
                                                   float* __restrict__ Cout) {
  __shared__ u16 As[128 * 64];
  __shared__ u16 Bs[128 * 64];
  const int K = 1024, N = 1024;
  const int tid = threadIdx.x;
  const int l = tid & 63;
  const int wid = tid >> 6;
  const int bid = blockIdx.x;
  const int swz = (bid & 7) * 64 + (bid >> 3); // 512 = 8 * 64
  const int m0 = (swz >> 3) * 128;
  const int n0 = (swz & 7) * 128;
  const int wr = wid >> 1, wc = wid & 1;
  const int r = l & 15, kg = l >> 4;
  f32x4 acc[4][4] = {};
  char* AsB = (char*)As;
  char* BsB = (char*)Bs;
  const int arow = l >> 3;
  const int agran = (l & 7) ^ arow;

  for (int kt = 0; kt < K; kt += 64) {
#pragma unroll
    for (int cc = 0; cc < 4; ++cc) {
      int c = wid + (cc << 2);
      int rowi = (c << 3) + arow;
      const char* ga = (const char*)A + ((size_t)(m0 + rowi) * K + kt) * 2 + agran * 16;
      async_copy16(AsB + c * 1024, ga);
      const char* gb = (const char*)Bw + ((size_t)(n0 + rowi) * K + kt) * 2 + agran * 16;
      async_copy16(BsB + c * 1024, gb);
    }
    __syncthreads();
#pragma unroll
    for (int half = 0; half < 2; ++half) {
      const int g = ((half << 2) + kg) ^ (r & 7);
      bf16x8 af[4], bf[4];
#pragma unroll
      for (int i = 0; i < 4; ++i) {
        af[i] = *(const bf16x8*)(AsB + (wr * 64 + i * 16 + r) * 128 + g * 16);
        bf[i] = *(const bf16x8*)(BsB + (wc * 64 + i * 16 + r) * 128 + g * 16);
      }
#pragma unroll
      for (int i = 0; i < 4; ++i)
#pragma unroll
        for (int j = 0; j < 4; ++j)
          acc[i][j] = MFMA16(af[i], bf[j], acc[i][j]);
    }
    __syncthreads();
  }
#pragma unroll
  for (int i = 0; i < 4; ++i) {
#pragma unroll
    for (int j = 0; j < 4; ++j) {
      const int col = n0 + wc * 64 + j * 16 + r;
      const float bvv = bias[col];
      const int row0 = m0 + wr * 64 + i * 16 + kg * 4;
#pragma unroll
      for (int jj = 0; jj < 4; ++jj)
        Cout[(size_t)(row0 + jj) * N + col] = acc[i][j][jj] + bvv;
    }
  }
}

// ---------------- flash attention v12: round-9 pipeline + precomputed LDS offsets ----------------
// Round-9 structure exactly (KVB=64, 4 blocks/CU, counted vmcnt, raw barriers, VALU rsum)
// + the 16 swizzled LDS read offsets precomputed once (lane-invariant across tiles) and
// the main loop pair-unrolled so buffer bases are compile-time LDS constants.
// NO extra f32 state (ones-MFMA/zc/static dbuf all regressed: register-pressure knee).
#define KVB 64
#define NT (SEQ / KVB)

__global__ __launch_bounds__(256, 4) void attn_kernel(const u16* __restrict__ Q,
                                                      const u16* __restrict__ K,
                                                      const u16* __restrict__ Vt,
                                                      u16* __restrict__ O) {
  __shared__ alignas(16) u16 Ks[2][KVB * 64]; // 2 x 8KB
  __shared__ alignas(16) u16 Vs[2][64 * KVB]; // 2 x 8KB
  const int tid = threadIdx.x;
  const int l = tid & 63;
  const int wid = tid >> 6;
  const int qg = l & 31;     // q row within wave
  const int half = l >> 5;
  // XCD-chunked grid: each XCD gets 128 consecutive swz = 8 bh values (K/V L2-resident)
  const int bid = blockIdx.x;
  const int swz = (bid & 7) * 128 + (bid >> 3);
  const int qt = swz & 15;   // 0..15
  const int bh = swz >> 4;   // 0..63
  const int b = bh >> 4, h = bh & 15;

  // ---- stage geometry: wave handles K chunks {wid, wid+4} and V chunks {wid, wid+4}
  const int srow = l >> 3, slot = l & 7;
  const int r0 = (wid << 3) + srow;
  const int r1 = ((wid + 4) << 3) + srow;
  const int sw0 = (r0 ^ (r0 >> 3)) & 7;
  const int sw1 = (r1 ^ (r1 >> 3)) & 7;
  const u16* pK0 = K + ((size_t)(b * SEQ) + r0) * D_MODEL + h * 64 + (slot ^ sw0) * 8;
  const u16* pK1 = K + ((size_t)(b * SEQ) + r1) * D_MODEL + h * 64 + (slot ^ sw1) * 8;
  const u16* pV0 = Vt + ((size_t)(bh * 64) + r0) * SEQ + (slot ^ sw0) * 8;
  const u16* pV1 = Vt + ((size_t)(bh * 64) + r1) * SEQ + (slot ^ sw1) * 8;
  const int ldsc0 = wid * 1024, ldsc1 = (wid + 4) * 1024;

  // Q fragments (pre-scaled by log2e at GEMM): col=q=l&31, k = dc*16 + half*8 + e
  bf16x8 qf[4];
  {
    const u16* q0 = Q + ((size_t)(b * SEQ + qt * 128 + wid * 32 + qg)) * D_MODEL + h * 64 + half * 8;
#pragma unroll
    for (int dc = 0; dc < 4; ++dc) qf[dc] = *(const bf16x8*)(q0 + dc * 16);
  }

  // precomputed LDS byte offsets (lane-invariant across tiles): 16 ints
  int koff[2][4], voff[2][2][2];
#pragma unroll
  for (int t32 = 0; t32 < 2; ++t32) {
    const int rowK = t32 * 32 + qg;
    const int swk = (rowK ^ (rowK >> 3)) & 7;
#pragma unroll
    for (int dc = 0; dc < 4; ++dc)
      koff[t32][dc] = rowK * 128 + (((dc * 2 + half) ^ swk) << 4);
#pragma unroll
    for (int cc = 0; cc < 2; ++cc) {
      const int qw = ((t32 * 2 + cc) << 1) + half;
#pragma unroll
      for (int dt = 0; dt < 2; ++dt) {
        const int rowV = dt * 32 + qg;
        voff[t32][cc][dt] = rowV * 128 + ((qw ^ ((rowV ^ (rowV >> 3)) & 7)) << 4);
      }
    }
  }

  f32x16 oacc[2] = {};
  float lrun = 0.f;

  auto stage = [&](int bufi) {
    char* KsX = (char*)Ks[bufi];
    char* VsX = (char*)Vs[bufi];
    async_copy16(KsX + ldsc0, pK0);
    async_copy16(KsX + ldsc1, pK1);
    async_copy16(VsX + ldsc0, pV0);
    async_copy16(VsX + ldsc1, pV1);
    pK0 += (size_t)KVB * D_MODEL;
    pK1 += (size_t)KVB * D_MODEL;
    pV0 += KVB;
    pV1 += KVB;
  };

  auto process = [&](const char* KsC, const char* VsC) {
    // S'^T[kv][q] = K·(log2e·q-hat): lane holds q=l&31, kv=(reg&3)+8*(reg>>2)+4*half (+32*t32)
    f32x16 st[2] = {};
    __builtin_amdgcn_s_setprio(1);
#pragma unroll
    for (int t32 = 0; t32 < 2; ++t32)
#pragma unroll
      for (int dc = 0; dc < 4; ++dc) {
        bf16x8 kf = *(const bf16x8*)(KsC + koff[t32][dc]);
        st[t32] = MFMA32(kf, qf[dc], st[t32]);
      }
    __builtin_amdgcn_s_setprio(0);

    // p = exp2(s')  (global e^1 factor cancels between numerator and denominator)
    float rs0 = 0.f, rs1 = 0.f, rs2 = 0.f, rs3 = 0.f;
#pragma unroll
    for (int t32 = 0; t32 < 2; ++t32)
#pragma unroll
      for (int rr = 0; rr < 16; rr += 4) {
        float p0 = __builtin_amdgcn_exp2f(st[t32][rr + 0]);
        float p1 = __builtin_amdgcn_exp2f(st[t32][rr + 1]);
        float p2 = __builtin_amdgcn_exp2f(st[t32][rr + 2]);
        float p3 = __builtin_amdgcn_exp2f(st[t32][rr + 3]);
        st[t32][rr + 0] = p0; st[t32][rr + 1] = p1;
        st[t32][rr + 2] = p2; st[t32][rr + 3] = p3;
        rs0 += p0; rs1 += p1; rs2 += p2; rs3 += p3;
      }
    lrun += (rs0 + rs1) + (rs2 + rs3);

    // PV: O^T[dh][q] += V^T[dh][kv] * P[q][kv]
#pragma unroll
    for (int t32 = 0; t32 < 2; ++t32) {
#pragma unroll
      for (int cc = 0; cc < 2; ++cc) {
        const int base = cc * 8;
        u32 wA = cvtpk_bf16(st[t32][base + 0], st[t32][base + 1]);
        u32 wB = cvtpk_bf16(st[t32][base + 2], st[t32][base + 3]);
        u32 wC = cvtpk_bf16(st[t32][base + 4], st[t32][base + 5]);
        u32 wD = cvtpk_bf16(st[t32][base + 6], st[t32][base + 7]);
        permswap(wA, wC);
        permswap(wB, wD);
        u32x4 pw = {wA, wB, wC, wD};
        bf16x8 pf = __builtin_bit_cast(bf16x8, pw);
        __builtin_amdgcn_s_setprio(1);
#pragma unroll
        for (int dt = 0; dt < 2; ++dt) {
          bf16x8 vf = *(const bf16x8*)(VsC + voff[t32][cc][dt]);
          oacc[dt] = MFMA32(vf, pf, oacc[dt]);
        }
        __builtin_amdgcn_s_setprio(0);
      }
    }
  };

  // prologue: stage tiles 0 and 1, one full drain (also covers Q-frag loads)
  stage(0);
  stage(1);
  VMCNT(0);
  wg_barrier();

  // pair-unrolled main loop: tiles 0..NT-3 (buffer base compile-time per copy)
  for (int tp = 0; tp < NT / 2 - 1; ++tp) {
    VMCNT(4);               // tile 2tp landed; tile 2tp+1 stays in flight
    wg_barrier();
    process((const char*)Ks[0], (const char*)Vs[0]);
    wg_barrier();
    stage(0);               // tile 2tp+2
    VMCNT(4);
    wg_barrier();
    process((const char*)Ks[1], (const char*)Vs[1]);
    wg_barrier();
    stage(1);               // tile 2tp+3
  }
  // tile NT-2 (buf0): already staged, nothing more to stage
  VMCNT(4);
  wg_barrier();
  process((const char*)Ks[0], (const char*)Vs[0]);
  wg_barrier();
  // tile NT-1 (buf1): full drain
  VMCNT(0);
  wg_barrier();
  process((const char*)Ks[1], (const char*)Vs[1]);

  // epilogue: denom = own-half sum + other-half sum; pack pairs, u32 stores
  lrun += __shfl_xor(lrun, 32);
  const float inv = 1.0f / lrun;
  u32* orow = (u32*)(O + ((size_t)(b * SEQ + qt * 128 + wid * 32 + qg)) * D_MODEL + h * 64);
#pragma unroll
  for (int dt = 0; dt < 2; ++dt)
#pragma unroll
    for (int w = 0; w < 8; ++w) {
      const int dh = dt * 32 + (w & 1) * 2 + 8 * (w >> 1) + 4 * half;
      u32 pk = cvtpk_bf16(oacc[dt][2 * w] * inv, oacc[dt][2 * w + 1] * inv);
      orow[dh >> 1] = pk;
    }
}

// ---------------- launch ----------------
extern "C" void kernel_launch(void* const* d_in, const int* in_sizes, int n_in,
                              void* d_out, int out_size, void* d_ws, size_t ws_size,
                              hipStream_t stream) {
  const float* x   = (const float*)d_in[0];
  const float* ctx = (const float*)d_in[1];
  const float* Wq  = (const float*)d_in[2];
  const float* bq  = (const float*)d_in[3];
  const float* Wk  = (const float*)d_in[4];
  const float* bk  = (const float*)d_in[5];
  const float* Wv  = (const float*)d_in[6];
  const float* bv  = (const float*)d_in[7];
  const float* Wo  = (const float*)d_in[8];
  const float* bo  = (const float*)d_in[9];
  float* out = (float*)d_out;

  const size_t NTOK = (size_t)MTOT * D_MODEL; // 8M elems
  const size_t WSZ = (size_t)D_MODEL * D_MODEL;
  u16* xb  = (u16*)d_ws;       // x bf16; later reused as attention output
  u16* cb  = xb + NTOK;
  u16* wqb = cb + NTOK;
  u16* wkb = wqb + WSZ;        // wk,wv adjacent -> fused [K|V] GEMM B-panel
  u16* wvb = wkb + WSZ;
  u16* wob = wvb + WSZ;
  u16* Qb  = wob + WSZ;
  u16* Kb  = Qb + NTOK;
  u16* Vtb = Kb + NTOK;        // [b*16+h][dh][tok]
  (void)in_sizes; (void)n_in; (void)out_size; (void)ws_size;

  dim3 blk(256);
  cvt_all<<<2048, blk, 0, stream>>>(x, ctx, Wq, Wk, Wv, Wo, xb, cb, wqb, wkb, wvb, wob);

  gemm_qkv<<<1536, blk, 0, stream>>>(xb, cb, wqb, wkb, bq, bk, bv, Qb, Kb, Vtb);

  attn_kernel<<<1024, blk, 0, stream>>>(Qb, Kb, Vtb, xb);

  gemm_out<<<512, blk, 0, stream>>>(xb, wob, bo, out);
}